// Round 1
// baseline (1087.310 us; speedup 1.0000x reference)
//
#include <hip/hip_runtime.h>
#include <math.h>

#define D 512
#define C 128
#define MARGIN 0.1f
#define EPS 1e-12f

// ---------------------------------------------------------------------------
// K1: segment sums + counts. One block per (class, col-half). Each wave owns
// 64 columns; scans all labels with __ballot, accumulates matching rows in a
// register. Deterministic, atomic-free; writes every sums/cnts element.
// ---------------------------------------------------------------------------
__global__ __launch_bounds__(256) void seg_sums(
    const float* __restrict__ emb, const int* __restrict__ labels, int B,
    float* __restrict__ sums, float* __restrict__ cnts) {
  int c = blockIdx.x >> 1, half = blockIdx.x & 1;
  int t = threadIdx.x, w = t >> 6, lane = t & 63;
  int col = half * 256 + w * 64 + lane;
  float acc = 0.f;
  int cnt = 0;
  for (int rb = 0; rb < B; rb += 64) {
    int lab = labels[rb + lane];
    unsigned long long m = __ballot(lab == c);
    cnt += __popcll(m);
    while (m) {
      int j = __builtin_ctzll(m);
      m &= m - 1;
      acc += emb[(size_t)(rb + j) * D + col];
    }
  }
  sums[c * D + col] = acc;
  if (half == 0 && t == 0) cnts[c] = (float)cnt;
}

// ---------------------------------------------------------------------------
// K2: fused diff-build + X@M + self-dot. Block = 64 rows (pos blocks then neg
// blocks). diff rows computed during staging (gathers S[label], scales).
// X staged fp32 [64][516] in LDS (full K). M tiled [64][68]. 4x4 register
// blocking (16x16 thread grid), shuffle-reduce the contraction over tc lanes.
// ---------------------------------------------------------------------------
#define ROWS 64
#define XSTR 516  // 516 % 32 == 4 -> 2-way bank alias only (free)

__global__ __launch_bounds__(256) void mahal_d2(
    const float* __restrict__ anchor, const float* __restrict__ emb,
    const float* __restrict__ M, const int* __restrict__ labels,
    const int* __restrict__ neg_labels, const float* __restrict__ sums,
    const float* __restrict__ cnts, int B, float* __restrict__ d2out) {
  __shared__ float X[ROWS * XSTR];   // 132096 B
  __shared__ float Ml[64 * 68];      // 17408 B
  __shared__ float d2part[ROWS];

  int bid = blockIdx.x;
  int nRowBlocks = B / ROWS;
  int isNeg = bid >= nRowBlocks;
  int rowbase = (isNeg ? bid - nRowBlocks : bid) * ROWS;
  int t = threadIdx.x;

  // ---- stage diff rows into LDS (coalesced: 4 g-lanes cover 64B runs) ----
  {
    int r = t >> 2, g = t & 3;
    int R = rowbase + r;
    float scale;
    const float4* s4;
    if (!isNeg) {
      int lab = labels[R];
      scale = 1.f / fmaxf(cnts[lab] - 1.f, 1.f);
      s4 = (const float4*)(sums + (size_t)lab * D);
    } else {
      int lab = neg_labels[R];
      scale = 1.f / fmaxf(cnts[lab], 1.f);
      s4 = (const float4*)(sums + (size_t)lab * D);
    }
    const float4* a4 = (const float4*)(anchor + (size_t)R * D);
    const float4* e4 = (const float4*)(emb + (size_t)R * D);
    float4* xl = (float4*)(X + r * XSTR);
#pragma unroll 8
    for (int ii = 0; ii < 32; ++ii) {
      int cidx = ii * 4 + g;  // float4 index within the row
      float4 a = a4[cidx], s = s4[cidx];
      float4 d;
      if (!isNeg) {
        float4 e = e4[cidx];
        d.x = a.x - scale * (s.x - e.x);
        d.y = a.y - scale * (s.y - e.y);
        d.z = a.z - scale * (s.z - e.z);
        d.w = a.w - scale * (s.w - e.w);
      } else {
        d.x = a.x - scale * s.x;
        d.y = a.y - scale * s.y;
        d.z = a.z - scale * s.z;
        d.w = a.w - scale * s.w;
      }
      xl[cidx] = d;
    }
  }
  __syncthreads();
  if (t < ROWS) d2part[t] = 0.f;

  int tc = t & 15, tr = t >> 4;  // 16x16 thread grid: rows tr*4..+3, cols tc*4..+3

  for (int cc = 0; cc < 8; ++cc) {
    float acc[4][4] = {{0.f}};
    for (int kk = 0; kk < 8; ++kk) {
      // stage M[kk*64..+63][cc*64..+63]
      {
        int kr = t >> 2, seg = t & 3;
        const float4* mg =
            (const float4*)(M + (size_t)(kk * 64 + kr) * D + cc * 64 + seg * 16);
        float4* md = (float4*)(Ml + kr * 68 + seg * 16);
#pragma unroll
        for (int q = 0; q < 4; ++q) md[q] = mg[q];
      }
      __syncthreads();
#pragma unroll 8
      for (int k = 0; k < 64; ++k) {
        float4 m4 = *(const float4*)(Ml + k * 68 + tc * 4);
#pragma unroll
        for (int j = 0; j < 4; ++j) {
          float xv = X[(tr * 4 + j) * XSTR + kk * 64 + k];
          acc[j][0] = fmaf(xv, m4.x, acc[j][0]);
          acc[j][1] = fmaf(xv, m4.y, acc[j][1]);
          acc[j][2] = fmaf(xv, m4.z, acc[j][2]);
          acc[j][3] = fmaf(xv, m4.w, acc[j][3]);
        }
      }
      __syncthreads();
    }
    // contract Y-chunk with X-chunk, reduce across the 16 tc lanes
#pragma unroll
    for (int j = 0; j < 4; ++j) {
      const float* xr = X + (tr * 4 + j) * XSTR + cc * 64 + tc * 4;
      float v = acc[j][0] * xr[0] + acc[j][1] * xr[1] + acc[j][2] * xr[2] +
                acc[j][3] * xr[3];
      v += __shfl_xor(v, 1);
      v += __shfl_xor(v, 2);
      v += __shfl_xor(v, 4);
      v += __shfl_xor(v, 8);
      if (tc == 0) d2part[tr * 4 + j] += v;  // unique row per (tr,j) thread
    }
  }
  __syncthreads();
  if (t < ROWS) d2out[(isNeg ? B : 0) + rowbase + t] = d2part[t];
}

// ---------------------------------------------------------------------------
// K3: per-block partial of relu(pos_d - neg_d + margin)
// ---------------------------------------------------------------------------
__global__ __launch_bounds__(256) void loss_partial(
    const float* __restrict__ d2, int B, float* __restrict__ partial) {
  int i = blockIdx.x * blockDim.x + threadIdx.x;
  float v = 0.f;
  if (i < B) {
    float dp = sqrtf(fmaxf(d2[i], 0.f) + EPS);
    float dn = sqrtf(fmaxf(d2[B + i], 0.f) + EPS);
    v = fmaxf(dp - dn + MARGIN, 0.f);
  }
  for (int off = 32; off; off >>= 1) v += __shfl_down(v, off);
  __shared__ float ws[4];
  int w = threadIdx.x >> 6, lane = threadIdx.x & 63;
  if (lane == 0) ws[w] = v;
  __syncthreads();
  if (threadIdx.x == 0) partial[blockIdx.x] = ws[0] + ws[1] + ws[2] + ws[3];
}

// K4: final mean
__global__ __launch_bounds__(256) void loss_final(
    const float* __restrict__ partial, int n, int B, float* __restrict__ out) {
  float v = (threadIdx.x < n) ? partial[threadIdx.x] : 0.f;
  for (int off = 32; off; off >>= 1) v += __shfl_down(v, off);
  __shared__ float ws[4];
  int w = threadIdx.x >> 6, lane = threadIdx.x & 63;
  if (lane == 0) ws[w] = v;
  __syncthreads();
  if (threadIdx.x == 0) out[0] = (ws[0] + ws[1] + ws[2] + ws[3]) / (float)B;
}

extern "C" void kernel_launch(void* const* d_in, const int* in_sizes, int n_in,
                              void* d_out, int out_size, void* d_ws,
                              size_t ws_size, hipStream_t stream) {
  const float* anchor = (const float*)d_in[0];
  const float* emb = (const float*)d_in[1];
  const float* M = (const float*)d_in[2];
  const int* labels = (const int*)d_in[3];
  const int* negl = (const int*)d_in[4];
  int B = in_sizes[3];  // 32768

  float* ws = (float*)d_ws;
  float* sums = ws;                 // C*D
  float* cnts = ws + C * D;         // C
  float* d2 = cnts + C;             // 2*B  (pos then neg)
  float* partial = d2 + 2 * B;      // B/256
  float* out = (float*)d_out;

  seg_sums<<<2 * C, 256, 0, stream>>>(emb, labels, B, sums, cnts);
  mahal_d2<<<2 * (B / ROWS), 256, 0, stream>>>(anchor, emb, M, labels, negl,
                                               sums, cnts, B, d2);
  loss_partial<<<B / 256, 256, 0, stream>>>(d2, B, partial);
  loss_final<<<1, 256, 0, stream>>>(partial, B / 256, B, out);
}

// Round 2
// 418.266 us; speedup vs baseline: 2.5996x; 2.5996x over previous
//
#include <hip/hip_runtime.h>
#include <math.h>

#define D 512
#define C 128
#define B_TOT 32768
#define MARGIN 0.1f
#define EPS 1e-12f

typedef __attribute__((ext_vector_type(8))) short short8;
typedef __attribute__((ext_vector_type(16))) float f32x16;

__device__ inline unsigned short f2bf(float f) {
  union { float f; unsigned u; } v; v.f = f;
  unsigned r = v.u + 0x7fff + ((v.u >> 16) & 1);   // RNE
  return (unsigned short)(r >> 16);
}
__device__ inline float bf2f(unsigned short h) {
  union { unsigned u; float f; } v; v.u = ((unsigned)h) << 16; return v.f;
}

__device__ inline void llds16(void* lds, const void* g) {
  __builtin_amdgcn_global_load_lds(
      (const __attribute__((address_space(1))) unsigned int*)g,
      (__attribute__((address_space(3))) unsigned int*)lds, 16, 0, 0);
}

// ---------------------------------------------------------------------------
// prep_m: cov_inv (fp32 [n][k], symmetric) -> Mh/Ml bf16 in MFMA A-fragment
// linear layout: [s=k16 (32)][nt (16)][lane (64)][8 bf16] ; element =
// M[nt*32 + (lane&31)][s*16 + (lane>>5)*8 + j]
// ---------------------------------------------------------------------------
__global__ __launch_bounds__(256) void prep_m(
    const float* __restrict__ M, unsigned short* __restrict__ Mh,
    unsigned short* __restrict__ Ml) {
  int p = blockIdx.x * 4 + (threadIdx.x >> 6);  // piece 0..511
  int lane = threadIdx.x & 63;
  int s = p >> 4, nt = p & 15;
  int n = nt * 32 + (lane & 31), k0 = s * 16 + (lane >> 5) * 8;
  const float4* mp4 = (const float4*)(M + (size_t)n * D + k0);
  float4 m0 = mp4[0], m1 = mp4[1];
  float mv[8] = {m0.x, m0.y, m0.z, m0.w, m1.x, m1.y, m1.z, m1.w};
  short8 hi, lo;
#pragma unroll
  for (int j = 0; j < 8; ++j) {
    unsigned short h = f2bf(mv[j]);
    hi[j] = (short)h;
    lo[j] = (short)f2bf(mv[j] - bf2f(h));
  }
  *(short8*)((char*)Mh + (((size_t)p * 64 + lane) << 4)) = hi;
  *(short8*)((char*)Ml + (((size_t)p * 64 + lane) << 4)) = lo;
}

// ---------------------------------------------------------------------------
// seg_part / seg_reduce: class sums+counts, atomic-free, 2048-way parallel
// ---------------------------------------------------------------------------
__global__ __launch_bounds__(256) void seg_part(
    const float* __restrict__ emb, const int* __restrict__ labels,
    float* __restrict__ psum, float* __restrict__ pcnt) {
  int b = blockIdx.x;                      // 128c * 2half * 8slice
  int c = b >> 4, half = (b >> 3) & 1, slice = b & 7;
  int t = threadIdx.x, w = t >> 6, lane = t & 63;
  int col = half * 256 + w * 64 + lane;
  int r0 = slice * 4096;
  float acc = 0.f; int cnt = 0;
  int lab = labels[r0 + lane];
  for (int ch = 0; ch < 64; ++ch) {
    int nxt = (ch < 63) ? labels[r0 + (ch + 1) * 64 + lane] : 0;
    unsigned long long m = __ballot(lab == c);
    cnt += __popcll(m);
    int rb = r0 + ch * 64;
    while (m) {
      int j = __builtin_ctzll(m); m &= m - 1;
      acc += emb[(size_t)(rb + j) * D + col];
    }
    lab = nxt;
  }
  psum[(size_t)(c * 8 + slice) * D + col] = acc;
  if (half == 0 && t == 0) pcnt[c * 8 + slice] = (float)cnt;
}

__global__ __launch_bounds__(256) void seg_reduce(
    const float* __restrict__ psum, const float* __restrict__ pcnt,
    float* __restrict__ sums, float* __restrict__ cnts) {
  int c = blockIdx.x, t = threadIdx.x;
  for (int h = 0; h < 2; ++h) {
    int col = h * 256 + t;
    float s = 0.f;
#pragma unroll
    for (int sl = 0; sl < 8; ++sl) s += psum[(size_t)(c * 8 + sl) * D + col];
    sums[(size_t)c * D + col] = s;
  }
  if (t == 0) {
    float s = 0.f;
    for (int sl = 0; sl < 8; ++sl) s += pcnt[c * 8 + sl];
    cnts[c] = s;
  }
}

// ---------------------------------------------------------------------------
// build_x: per 32-row tile, compute diff x (fp32), emit:
//  - Xf  : bf16(x) in B-fragment linear layout [s(32)][rtile(1024)][lane][8]
//          element = x[rtile*32 + (lane&31)][s*16 + (lane>>5)*8 + j]
//  - Rt  : (2x - h) fp32 TRANSPOSED [k(512)][r(32768)]  (coalesced writes)
// processed in two k-halves so the LDS x-tile (stride 257) fits in 33 KB.
// ---------------------------------------------------------------------------
__global__ __launch_bounds__(256) void build_x(
    const float* __restrict__ anchor, const float* __restrict__ emb,
    const int* __restrict__ labels, const float* __restrict__ sums,
    const float* __restrict__ cnts, int isNeg,
    unsigned short* __restrict__ Xf, float* __restrict__ Rt) {
  __shared__ float xs[32 * 257];
  const int t = threadIdx.x;
  const int rblk = blockIdx.x;   // rows rblk*32 .. +31
  const int rl = t >> 3, seg = t & 7;
  const int rg = rblk * 32 + rl;
  const int lab = labels[rg];
  const float cnt = cnts[lab];
  const float scale = isNeg ? 1.f / fmaxf(cnt, 1.f) : 1.f / fmaxf(cnt - 1.f, 1.f);

  for (int kh = 0; kh < 2; ++kh) {
    // phase 1: compute x for k in [kh*256, kh*256+256)
    {
      const int kbase = kh * 256 + seg * 32;   // 8 float4 per thread
      const float4* a4 = (const float4*)(anchor + (size_t)rg * D + kbase);
      const float4* s4 = (const float4*)(sums + (size_t)lab * D + kbase);
      const float4* e4 = (const float4*)(emb + (size_t)rg * D + kbase);
      float* xr = xs + rl * 257 + seg * 32;
#pragma unroll
      for (int i = 0; i < 8; ++i) {
        float4 a = a4[i], sv = s4[i];
        float4 x;
        if (!isNeg) {
          float4 e = e4[i];
          x.x = a.x - scale * (sv.x - e.x);
          x.y = a.y - scale * (sv.y - e.y);
          x.z = a.z - scale * (sv.z - e.z);
          x.w = a.w - scale * (sv.w - e.w);
        } else {
          x.x = a.x - scale * sv.x;
          x.y = a.y - scale * sv.y;
          x.z = a.z - scale * sv.z;
          x.w = a.w - scale * sv.w;
        }
        xr[i * 4 + 0] = x.x; xr[i * 4 + 1] = x.y;
        xr[i * 4 + 2] = x.z; xr[i * 4 + 3] = x.w;
      }
    }
    __syncthreads();
    // phase 2a: Rt columns (fp32, transposed, coalesced 128B runs)
    {
      int r = t & 31, kg = t >> 5;   // kg 0..7, 32 k each
      const int rg0 = rblk * 32;
      for (int j = 0; j < 32; ++j) {
        int kl = kg * 32 + j;
        float x = xs[r * 257 + kl];
        float h = bf2f(f2bf(x));
        Rt[(size_t)(kh * 256 + kl) * B_TOT + rg0 + r] = 2.f * x - h;
      }
    }
    // phase 2b: Xf fragments (16 k16-pieces this half)
    {
      int l = t & 63, w = t >> 6;
      int r = l & 31, koff = (l >> 5) * 8;
#pragma unroll
      for (int si = 0; si < 4; ++si) {
        int sl = w * 4 + si;             // 0..15 within half
        int s = kh * 16 + sl;            // global k16 index
        short8 pk;
#pragma unroll
        for (int j = 0; j < 8; ++j)
          pk[j] = (short)f2bf(xs[r * 257 + sl * 16 + koff + j]);
        *(short8*)((char*)Xf + ((((size_t)s * 1024 + rblk) * 64 + l) << 4)) = pk;
      }
    }
    __syncthreads();
  }
}

// ---------------------------------------------------------------------------
// gemm_d2: Z[n,r] = sum_k M[n,k]*Xhi[r,k] via mfma_f32_32x32x16_bf16 with
// M split hi/lo; then d2[r] = sum_n Z[n,r] * Rt[n][r].
// Block: 128 rows x full N=512, K=512 in 16 steps of 32. 8 waves, each
// 64n x 128r (2x4 tiles of 32x32). LDS 144KB: Mh/Ml dbuf 32KB chunks +
// X dbuf 8KB chunks, all fragment-linear (conflict-free, global_load_lds).
// ---------------------------------------------------------------------------
#define GW_MH 0
#define GW_ML 65536
#define GW_XB 131072
#define GEMM_LDS 147456

__global__ __launch_bounds__(512, 2) void gemm_d2(
    const unsigned short* __restrict__ Mh, const unsigned short* __restrict__ Ml,
    const unsigned short* __restrict__ Xf, const float* __restrict__ Rt,
    float* __restrict__ d2out) {
  __shared__ char smem[GEMM_LDS];
  const int t = threadIdx.x, w = t >> 6, lane = t & 63;
  const int rblk = blockIdx.x;               // 0..255 (128 rows each)

  f32x16 acc[2][4];
#pragma unroll
  for (int nt = 0; nt < 2; ++nt)
#pragma unroll
    for (int rt = 0; rt < 4; ++rt)
#pragma unroll
      for (int i = 0; i < 16; ++i) acc[nt][rt][i] = 0.f;

  const unsigned short* Mg = (w < 4) ? Mh : Ml;
  char* ldsMbase = smem + ((w < 4) ? GW_MH : GW_ML);
  const int mbase = (w & 3) * 8;
  const int xkh = w >> 2, xrt = w & 3;

  auto stage = [&](int s, int buf) {
    char* ldsM = ldsMbase + buf * 32768;
#pragma unroll
    for (int p = 0; p < 8; ++p) {
      int mi = mbase + p, kh = mi >> 4, nt = mi & 15;
      llds16(ldsM + mi * 1024,
             (const char*)Mg + ((((size_t)((2 * s + kh) * 16 + nt)) * 64 + lane) << 4));
    }
    llds16(smem + GW_XB + buf * 8192 + w * 1024,
           (const char*)Xf +
               ((((size_t)(2 * s + xkh) * 1024 + (rblk * 4 + xrt)) * 64 + lane) << 4));
  };

  stage(0, 0);
  __syncthreads();
  int buf = 0;
  for (int s = 0; s < 16; ++s) {
    if (s < 15) stage(s + 1, buf ^ 1);
#pragma unroll
    for (int kh = 0; kh < 2; ++kh) {
      short8 ah[2], al[2], xb[4];
#pragma unroll
      for (int nt = 0; nt < 2; ++nt) {
        int po = (kh * 16 + 2 * w + nt) * 1024 + lane * 16;
        ah[nt] = *(const short8*)(smem + GW_MH + buf * 32768 + po);
        al[nt] = *(const short8*)(smem + GW_ML + buf * 32768 + po);
      }
#pragma unroll
      for (int rt = 0; rt < 4; ++rt)
        xb[rt] = *(const short8*)(smem + GW_XB + buf * 8192 + (kh * 4 + rt) * 1024 + lane * 16);
#pragma unroll
      for (int nt = 0; nt < 2; ++nt)
#pragma unroll
        for (int rt = 0; rt < 4; ++rt) {
          acc[nt][rt] = __builtin_amdgcn_mfma_f32_32x32x16_bf16(ah[nt], xb[rt], acc[nt][rt], 0, 0, 0);
          acc[nt][rt] = __builtin_amdgcn_mfma_f32_32x32x16_bf16(al[nt], xb[rt], acc[nt][rt], 0, 0, 0);
        }
    }
    __syncthreads();
    buf ^= 1;
  }

  // epilogue: d2[r] += Z[n,r] * Rt[n][r]
  float d2l[4] = {0.f, 0.f, 0.f, 0.f};
  const int l31 = lane & 31, lh = lane >> 5;
#pragma unroll
  for (int nt = 0; nt < 2; ++nt) {
    int nbase = (2 * w + nt) * 32 + 4 * lh;
#pragma unroll
    for (int i = 0; i < 16; ++i) {
      int n = nbase + (i & 3) + 8 * (i >> 2);
      const float* rp = Rt + (size_t)n * B_TOT + rblk * 128 + l31;
#pragma unroll
      for (int rt = 0; rt < 4; ++rt)
        d2l[rt] = fmaf(acc[nt][rt][i], rp[rt * 32], d2l[rt]);
    }
  }
#pragma unroll
  for (int rt = 0; rt < 4; ++rt) d2l[rt] += __shfl_xor(d2l[rt], 32);

  float* d2s = (float*)smem;  // reuse LDS (disjoint writes, then barrier)
  if (lane < 32) {
#pragma unroll
    for (int rt = 0; rt < 4; ++rt) d2s[w * 128 + rt * 32 + l31] = d2l[rt];
  }
  __syncthreads();
  if (t < 128) {
    float sum = 0.f;
#pragma unroll
    for (int ww = 0; ww < 8; ++ww) sum += d2s[ww * 128 + t];
    d2out[rblk * 128 + t] = sum;
  }
}

// ---------------------------------------------------------------------------
// loss reduction (unchanged from passing round-1 version)
// ---------------------------------------------------------------------------
__global__ __launch_bounds__(256) void loss_partial(
    const float* __restrict__ d2, int B, float* __restrict__ partial) {
  int i = blockIdx.x * blockDim.x + threadIdx.x;
  float v = 0.f;
  if (i < B) {
    float dp = sqrtf(fmaxf(d2[i], 0.f) + EPS);
    float dn = sqrtf(fmaxf(d2[B + i], 0.f) + EPS);
    v = fmaxf(dp - dn + MARGIN, 0.f);
  }
  for (int off = 32; off; off >>= 1) v += __shfl_down(v, off);
  __shared__ float ws[4];
  int w = threadIdx.x >> 6, lane = threadIdx.x & 63;
  if (lane == 0) ws[w] = v;
  __syncthreads();
  if (threadIdx.x == 0) partial[blockIdx.x] = ws[0] + ws[1] + ws[2] + ws[3];
}

__global__ __launch_bounds__(256) void loss_final(
    const float* __restrict__ partial, int n, int B, float* __restrict__ out) {
  float v = (threadIdx.x < n) ? partial[threadIdx.x] : 0.f;
  for (int off = 32; off; off >>= 1) v += __shfl_down(v, off);
  __shared__ float ws[4];
  int w = threadIdx.x >> 6, lane = threadIdx.x & 63;
  if (lane == 0) ws[w] = v;
  __syncthreads();
  if (threadIdx.x == 0) out[0] = (ws[0] + ws[1] + ws[2] + ws[3]) / (float)B;
}

extern "C" void kernel_launch(void* const* d_in, const int* in_sizes, int n_in,
                              void* d_out, int out_size, void* d_ws,
                              size_t ws_size, hipStream_t stream) {
  const float* anchor = (const float*)d_in[0];
  const float* emb = (const float*)d_in[1];
  const float* M = (const float*)d_in[2];
  const int* labels = (const int*)d_in[3];
  const int* negl = (const int*)d_in[4];

  char* ws = (char*)d_ws;
  size_t off = 0;
  auto alloc = [&](size_t bytes) {
    char* p = ws + off;
    off += (bytes + 255) & ~(size_t)255;
    return p;
  };
  unsigned short* Mh = (unsigned short*)alloc((size_t)512 * 512 * 2);
  unsigned short* Ml = (unsigned short*)alloc((size_t)512 * 512 * 2);
  float* sums = (float*)alloc((size_t)C * D * 4);
  float* cnts = (float*)alloc((size_t)C * 4);
  float* psum = (float*)alloc((size_t)C * 8 * D * 4);
  float* pcnt = (float*)alloc((size_t)C * 8 * 4);
  unsigned short* Xf = (unsigned short*)alloc((size_t)32 * 1024 * 64 * 16);  // 32 MB
  float* Rt = (float*)alloc((size_t)D * B_TOT * 4);                          // 64 MB
  float* d2 = (float*)alloc((size_t)2 * B_TOT * 4);
  float* lpart = (float*)alloc((size_t)(B_TOT / 256) * 4);

  prep_m<<<128, 256, 0, stream>>>(M, Mh, Ml);
  seg_part<<<2048, 256, 0, stream>>>(emb, labels, psum, pcnt);
  seg_reduce<<<128, 256, 0, stream>>>(psum, pcnt, sums, cnts);

  for (int pass = 0; pass < 2; ++pass) {
    const int* lab = pass ? negl : labels;
    build_x<<<1024, 256, 0, stream>>>(anchor, emb, lab, sums, cnts, pass, Xf, Rt);
    gemm_d2<<<256, 512, 0, stream>>>(Mh, Ml, Xf, Rt, d2 + pass * B_TOT);
  }

  loss_partial<<<B_TOT / 256, 256, 0, stream>>>(d2, B_TOT, lpart);
  loss_final<<<1, 256, 0, stream>>>(lpart, B_TOT / 256, B_TOT, (float*)d_out);
}

// Round 3
// 299.542 us; speedup vs baseline: 3.6299x; 1.3963x over previous
//
#include <hip/hip_runtime.h>
#include <math.h>

#define D 512
#define C 128
#define B_TOT 32768
#define MARGIN 0.1f
#define EPS 1e-12f

typedef __attribute__((ext_vector_type(8))) short short8;
typedef __attribute__((ext_vector_type(16))) float f32x16;

__device__ inline unsigned short f2bf(float f) {
  union { float f; unsigned u; } v; v.f = f;
  unsigned r = v.u + 0x7fff + ((v.u >> 16) & 1);   // RNE
  return (unsigned short)(r >> 16);
}
__device__ inline float bf2f(unsigned short h) {
  union { unsigned u; float f; } v; v.u = ((unsigned)h) << 16; return v.f;
}

__device__ inline void llds16(void* lds, const void* g) {
  __builtin_amdgcn_global_load_lds(
      (const __attribute__((address_space(1))) unsigned int*)g,
      (__attribute__((address_space(3))) unsigned int*)lds, 16, 0, 0);
}

// ---------------------------------------------------------------------------
// prep_m: cov_inv fp32 [n][k] -> Mh/Ml bf16 MFMA A-fragment linear layout:
// piece p = s*16 + nt ; element = M[nt*32+(lane&31)][s*16+(lane>>5)*8+j]
// ---------------------------------------------------------------------------
__global__ __launch_bounds__(256) void prep_m(
    const float* __restrict__ M, unsigned short* __restrict__ Mh,
    unsigned short* __restrict__ Ml) {
  int p = blockIdx.x * 4 + (threadIdx.x >> 6);  // piece 0..511
  int lane = threadIdx.x & 63;
  int s = p >> 4, nt = p & 15;
  int n = nt * 32 + (lane & 31), k0 = s * 16 + (lane >> 5) * 8;
  const float4* mp4 = (const float4*)(M + (size_t)n * D + k0);
  float4 m0 = mp4[0], m1 = mp4[1];
  float mv[8] = {m0.x, m0.y, m0.z, m0.w, m1.x, m1.y, m1.z, m1.w};
  short8 hi, lo;
#pragma unroll
  for (int j = 0; j < 8; ++j) {
    unsigned short h = f2bf(mv[j]);
    hi[j] = (short)h;
    lo[j] = (short)f2bf(mv[j] - bf2f(h));
  }
  *(short8*)((char*)Mh + (((size_t)p * 64 + lane) << 4)) = hi;
  *(short8*)((char*)Ml + (((size_t)p * 64 + lane) << 4)) = lo;
}

// ---------------------------------------------------------------------------
// seg_part / seg_reduce: class sums+counts, atomic-free
// ---------------------------------------------------------------------------
__global__ __launch_bounds__(256) void seg_part(
    const float* __restrict__ emb, const int* __restrict__ labels,
    float* __restrict__ psum, float* __restrict__ pcnt) {
  int b = blockIdx.x;                      // 128c * 2half * 8slice
  int c = b >> 4, half = (b >> 3) & 1, slice = b & 7;
  int t = threadIdx.x, w = t >> 6, lane = t & 63;
  int col = half * 256 + w * 64 + lane;
  int r0 = slice * 4096;
  float acc = 0.f; int cnt = 0;
  int lab = labels[r0 + lane];
  for (int ch = 0; ch < 64; ++ch) {
    int nxt = (ch < 63) ? labels[r0 + (ch + 1) * 64 + lane] : 0;
    unsigned long long m = __ballot(lab == c);
    cnt += __popcll(m);
    int rb = r0 + ch * 64;
    while (m) {
      int j = __builtin_ctzll(m); m &= m - 1;
      acc += emb[(size_t)(rb + j) * D + col];
    }
    lab = nxt;
  }
  psum[(size_t)(c * 8 + slice) * D + col] = acc;
  if (half == 0 && t == 0) pcnt[c * 8 + slice] = (float)cnt;
}

__global__ __launch_bounds__(256) void seg_reduce(
    const float* __restrict__ psum, const float* __restrict__ pcnt,
    float* __restrict__ sums, float* __restrict__ cnts) {
  int c = blockIdx.x, t = threadIdx.x;
  for (int h = 0; h < 2; ++h) {
    int col = h * 256 + t;
    float s = 0.f;
#pragma unroll
    for (int sl = 0; sl < 8; ++sl) s += psum[(size_t)(c * 8 + sl) * D + col];
    sums[(size_t)c * D + col] = s;
  }
  if (t == 0) {
    float s = 0.f;
    for (int sl = 0; sl < 8; ++sl) s += pcnt[c * 8 + sl];
    cnts[c] = s;
  }
}

// ---------------------------------------------------------------------------
// build_x2: BOTH passes fused. Per block: 32 rows. Every global access is a
// full-wave 1KB contiguous run (row uniform per wave -> coalesced gather).
// Writes bf16 B-fragment arrays Xfp/Xfn only (no fp32 residual array):
// element = x[g*32+(lane&31)][s*16+(lane>>5)*8+j] at ((s*1024+g)*64+lane)*16.
// ---------------------------------------------------------------------------
__global__ __launch_bounds__(256) void build_x2(
    const float* __restrict__ anchor, const float* __restrict__ emb,
    const int* __restrict__ labels, const int* __restrict__ negl,
    const float* __restrict__ sums, const float* __restrict__ cnts,
    unsigned short* __restrict__ Xfp, unsigned short* __restrict__ Xfn) {
  __shared__ float xsp[32 * 257], xsn[32 * 257];
  const int t = threadIdx.x, w = t >> 6, lane = t & 63;
  const int g = blockIdx.x;
  const int r = lane & 31, koff = (lane >> 5) * 8;

  for (int kh = 0; kh < 2; ++kh) {
    if (kh) __syncthreads();   // xs reuse: prior phase-2 reads done
    // phase 1: wave handles one row per iteration; 1KB contiguous per access
#pragma unroll 2
    for (int it = 0; it < 8; ++it) {
      int row = it * 4 + w;
      int R = g * 32 + row;
      int lp = labels[R], ln = negl[R];
      float sp = 1.f / fmaxf(cnts[lp] - 1.f, 1.f);
      float sn = 1.f / fmaxf(cnts[ln], 1.f);
      int c0 = kh * 256 + lane * 4;
      float4 a = *(const float4*)(anchor + (size_t)R * D + c0);
      float4 e = *(const float4*)(emb + (size_t)R * D + c0);
      float4 Sp = *(const float4*)(sums + (size_t)lp * D + c0);
      float4 Sn = *(const float4*)(sums + (size_t)ln * D + c0);
      float4 xp, xn;
      xp.x = a.x - sp * (Sp.x - e.x);  xn.x = a.x - sn * Sn.x;
      xp.y = a.y - sp * (Sp.y - e.y);  xn.y = a.y - sn * Sn.y;
      xp.z = a.z - sp * (Sp.z - e.z);  xn.z = a.z - sn * Sn.z;
      xp.w = a.w - sp * (Sp.w - e.w);  xn.w = a.w - sn * Sn.w;
      *(float4*)(xsp + row * 257 + lane * 4) = xp;
      *(float4*)(xsn + row * 257 + lane * 4) = xn;
    }
    __syncthreads();
    // phase 2: pack fragments; 1KB contiguous global writes per wave
#pragma unroll
    for (int c = 0; c < 8; ++c) {
      const float* xs = (c < 4) ? xsp : xsn;
      unsigned short* Xf = (c < 4) ? Xfp : Xfn;
      int sl = w * 4 + (c & 3);
      short8 pk;
#pragma unroll
      for (int j = 0; j < 8; ++j)
        pk[j] = (short)f2bf(xs[r * 257 + sl * 16 + koff + j]);
      int s = kh * 16 + sl;
      *(short8*)((char*)Xf + ((((size_t)s * 1024 + g) * 64 + lane) << 4)) = pk;
    }
  }
}

// ---------------------------------------------------------------------------
// gemm_d2f: fused pos+neg. Block = 64 rows (32 pos rt0 + 32 neg rt1), full
// N=K=512. d2[r] = sum_n h[n,r] * Z[n,r], Z = (Mh+Ml)*h  (e-correction
// dropped: per-sample sigma(d2)~0.14 -> mean-loss error ~2e-5).
// LDS 128KB: X-full 64KB resident + M k16-chunk double-buffered 64KB.
// Epilogue: Z transposed through LDS in two 256-n halves; h read from the
// resident X fragments with conflict-free b128 reads.
// ---------------------------------------------------------------------------
#define XL_OFF 0
#define ML_OFF 65536

__global__ __launch_bounds__(512, 2) void gemm_d2f(
    const unsigned short* __restrict__ Mh, const unsigned short* __restrict__ Ml,
    const unsigned short* __restrict__ Xfp, const unsigned short* __restrict__ Xfn,
    float* __restrict__ d2out) {
  __shared__ char smem[131072];
  const int t = threadIdx.x, w = t >> 6, lane = t & 63;
  const int g = blockIdx.x;
  const int lh = lane >> 5, rr = lane & 31;

  f32x16 acc[2][2];
#pragma unroll
  for (int nt = 0; nt < 2; ++nt)
#pragma unroll
    for (int rt = 0; rt < 2; ++rt)
#pragma unroll
      for (int i = 0; i < 16; ++i) acc[nt][rt][i] = 0.f;

  auto stageM = [&](int ks, int buf) {
#pragma unroll
    for (int c = 0; c < 4; ++c) {
      int idx = w * 4 + c;                       // 0..15 hi, 16..31 lo
      int nt = idx & 15;
      const unsigned short* src = (idx < 16) ? Mh : Ml;
      llds16(smem + ML_OFF + buf * 32768 + idx * 1024,
             (const char*)src + ((((size_t)ks * 16 + nt) * 64 + lane) << 4));
    }
  };

  // prologue: X-full (8 pieces/wave) + M step 0
#pragma unroll
  for (int c = 0; c < 8; ++c) {
    int piece = w * 8 + c;                       // = s*2 + rt
    int s = piece >> 1, rt = piece & 1;
    const unsigned short* src = rt ? Xfn : Xfp;
    llds16(smem + XL_OFF + piece * 1024,
           (const char*)src + ((((size_t)s * 1024 + g) * 64 + lane) << 4));
  }
  stageM(0, 0);
  __syncthreads();   // compiler emits vmcnt(0) before barrier

  int buf = 0;
  for (int s = 0; s < 32; ++s) {
    if (s < 31) stageM(s + 1, buf ^ 1);
    short8 ah[2], al[2], xb[2];
#pragma unroll
    for (int nt = 0; nt < 2; ++nt) {
      int pi = w * 2 + nt;
      ah[nt] = *(const short8*)(smem + ML_OFF + buf * 32768 + ((pi * 64 + lane) << 4));
      al[nt] = *(const short8*)(smem + ML_OFF + buf * 32768 + (((16 + pi) * 64 + lane) << 4));
    }
#pragma unroll
    for (int rt = 0; rt < 2; ++rt)
      xb[rt] = *(const short8*)(smem + XL_OFF + (((s * 2 + rt) * 64 + lane) << 4));
#pragma unroll
    for (int nt = 0; nt < 2; ++nt)
#pragma unroll
      for (int rt = 0; rt < 2; ++rt) {
        acc[nt][rt] = __builtin_amdgcn_mfma_f32_32x32x16_bf16(ah[nt], xb[rt], acc[nt][rt], 0, 0, 0);
        acc[nt][rt] = __builtin_amdgcn_mfma_f32_32x32x16_bf16(al[nt], xb[rt], acc[nt][rt], 0, 0, 0);
      }
    __syncthreads();
    buf ^= 1;
  }

  // ---- epilogue: d2[r] = sum_n h[n,r]*Z[n,r], two 256-n halves ----
  float* ZL = (float*)(smem + ML_OFF);          // 256 x 64 f32 = 64KB
  float d2acc = 0.f;
  const int rB = t & 63, ng = t >> 6;           // contraction roles
  const int rtB = rB >> 5;
  for (int H = 0; H < 2; ++H) {
    if ((w >> 2) == H) {                        // 4 waves own this n-half
#pragma unroll
      for (int nt = 0; nt < 2; ++nt)
#pragma unroll
        for (int i = 0; i < 16; ++i) {
          int nl = (w & 3) * 64 + nt * 32 + (i & 3) + 8 * (i >> 2) + 4 * lh;
#pragma unroll
          for (int rt = 0; rt < 2; ++rt)
            ZL[nl * 64 + rt * 32 + rr] = acc[nt][rt][i];
        }
    }
    __syncthreads();
#pragma unroll
    for (int j8 = 0; j8 < 4; ++j8) {
      int nl0 = ng * 32 + j8 * 8;
      int n0 = H * 256 + nl0;
      int sI = n0 >> 4, b3 = (n0 >> 3) & 1;     // h[n0..n0+7][rB] in one b128
      short8 hv = *(const short8*)(
          smem + XL_OFF + ((((sI * 2 + rtB) * 64) + (rB & 31) + 32 * b3) << 4));
#pragma unroll
      for (int q = 0; q < 8; ++q)
        d2acc += bf2f((unsigned short)hv[q]) * ZL[(nl0 + q) * 64 + rB];
    }
    __syncthreads();
  }
  float* DP = (float*)(smem + ML_OFF);
  DP[ng * 64 + rB] = d2acc;
  __syncthreads();
  if (t < 64) {
    float sv = 0.f;
#pragma unroll
    for (int k = 0; k < 8; ++k) sv += DP[k * 64 + t];
    int gi = g * 32 + (t & 31);
    d2out[(t >> 5) ? (B_TOT + gi) : gi] = sv;
  }
}

// ---------------------------------------------------------------------------
// loss reduction
// ---------------------------------------------------------------------------
__global__ __launch_bounds__(256) void loss_partial(
    const float* __restrict__ d2, int B, float* __restrict__ partial) {
  int i = blockIdx.x * blockDim.x + threadIdx.x;
  float v = 0.f;
  if (i < B) {
    float dp = sqrtf(fmaxf(d2[i], 0.f) + EPS);
    float dn = sqrtf(fmaxf(d2[B + i], 0.f) + EPS);
    v = fmaxf(dp - dn + MARGIN, 0.f);
  }
  for (int off = 32; off; off >>= 1) v += __shfl_down(v, off);
  __shared__ float ws[4];
  int w = threadIdx.x >> 6, lane = threadIdx.x & 63;
  if (lane == 0) ws[w] = v;
  __syncthreads();
  if (threadIdx.x == 0) partial[blockIdx.x] = ws[0] + ws[1] + ws[2] + ws[3];
}

__global__ __launch_bounds__(256) void loss_final(
    const float* __restrict__ partial, int n, int B, float* __restrict__ out) {
  float v = (threadIdx.x < n) ? partial[threadIdx.x] : 0.f;
  for (int off = 32; off; off >>= 1) v += __shfl_down(v, off);
  __shared__ float ws[4];
  int w = threadIdx.x >> 6, lane = threadIdx.x & 63;
  if (lane == 0) ws[w] = v;
  __syncthreads();
  if (threadIdx.x == 0) out[0] = (ws[0] + ws[1] + ws[2] + ws[3]) / (float)B;
}

extern "C" void kernel_launch(void* const* d_in, const int* in_sizes, int n_in,
                              void* d_out, int out_size, void* d_ws,
                              size_t ws_size, hipStream_t stream) {
  const float* anchor = (const float*)d_in[0];
  const float* emb = (const float*)d_in[1];
  const float* M = (const float*)d_in[2];
  const int* labels = (const int*)d_in[3];
  const int* negl = (const int*)d_in[4];

  char* ws = (char*)d_ws;
  size_t off = 0;
  auto alloc = [&](size_t bytes) {
    char* p = ws + off;
    off += (bytes + 255) & ~(size_t)255;
    return p;
  };
  unsigned short* Mh = (unsigned short*)alloc((size_t)512 * 512 * 2);
  unsigned short* Ml = (unsigned short*)alloc((size_t)512 * 512 * 2);
  float* sums = (float*)alloc((size_t)C * D * 4);
  float* cnts = (float*)alloc((size_t)C * 4);
  float* psum = (float*)alloc((size_t)C * 8 * D * 4);
  float* pcnt = (float*)alloc((size_t)C * 8 * 4);
  unsigned short* Xfp = (unsigned short*)alloc((size_t)32 * 1024 * 64 * 16);  // 32 MB
  unsigned short* Xfn = (unsigned short*)alloc((size_t)32 * 1024 * 64 * 16);  // 32 MB
  float* d2 = (float*)alloc((size_t)2 * B_TOT * 4);
  float* lpart = (float*)alloc((size_t)(B_TOT / 256) * 4);

  prep_m<<<128, 256, 0, stream>>>(M, Mh, Ml);
  seg_part<<<2048, 256, 0, stream>>>(emb, labels, psum, pcnt);
  seg_reduce<<<128, 256, 0, stream>>>(psum, pcnt, sums, cnts);
  build_x2<<<1024, 256, 0, stream>>>(anchor, emb, labels, negl, sums, cnts, Xfp, Xfn);
  gemm_d2f<<<1024, 512, 0, stream>>>(Mh, Ml, Xfp, Xfn, d2);
  loss_partial<<<B_TOT / 256, 256, 0, stream>>>(d2, B_TOT, lpart);
  loss_final<<<1, 256, 0, stream>>>(lpart, B_TOT / 256, B_TOT, (float*)d_out);
}

// Round 4
// 260.171 us; speedup vs baseline: 4.1792x; 1.1513x over previous
//
#include <hip/hip_runtime.h>
#include <math.h>

#define D 512
#define C 128
#define B_TOT 32768
#define MARGIN 0.1f
#define EPS 1e-12f

typedef __attribute__((ext_vector_type(4))) short short4v;
typedef __attribute__((ext_vector_type(8))) short short8;
typedef __attribute__((ext_vector_type(16))) float f32x16;

__device__ inline unsigned short f2bf(float f) {
  union { float f; unsigned u; } v; v.f = f;
  unsigned r = v.u + 0x7fff + ((v.u >> 16) & 1);   // RNE
  return (unsigned short)(r >> 16);
}
__device__ inline float bf2f(unsigned short h) {
  union { unsigned u; float f; } v; v.u = ((unsigned)h) << 16; return v.f;
}

__device__ inline void llds16(void* lds, const void* g) {
  __builtin_amdgcn_global_load_lds(
      (const __attribute__((address_space(1))) unsigned int*)g,
      (__attribute__((address_space(3))) unsigned int*)lds, 16, 0, 0);
}

// ---------------------------------------------------------------------------
// prep_m: cov_inv fp32 [n][k] -> Mh bf16 MFMA A-fragment linear layout
// (piece p = s*16 + nt ; element = M[nt*32+(lane&31)][s*16+(lane>>5)*8+j])
// plus Mld[512] = fp32 diagonal residual M[i][i] - bf16(M[i][i]).
// ---------------------------------------------------------------------------
__global__ __launch_bounds__(256) void prep_m(
    const float* __restrict__ M, unsigned short* __restrict__ Mh,
    float* __restrict__ Mld) {
  int p = blockIdx.x * 4 + (threadIdx.x >> 6);  // piece 0..511
  int lane = threadIdx.x & 63;
  int s = p >> 4, nt = p & 15;
  int n = nt * 32 + (lane & 31), k0 = s * 16 + (lane >> 5) * 8;
  const float4* mp4 = (const float4*)(M + (size_t)n * D + k0);
  float4 m0 = mp4[0], m1 = mp4[1];
  float mv[8] = {m0.x, m0.y, m0.z, m0.w, m1.x, m1.y, m1.z, m1.w};
  short8 hi;
#pragma unroll
  for (int j = 0; j < 8; ++j) hi[j] = (short)f2bf(mv[j]);
  *(short8*)((char*)Mh + (((size_t)p * 64 + lane) << 4)) = hi;
  if (blockIdx.x == 0) {
    for (int i = threadIdx.x; i < 512; i += 256) {
      float v = M[(size_t)i * 513];
      Mld[i] = v - bf2f(f2bf(v));
    }
  }
}

// ---------------------------------------------------------------------------
// seg_part / seg_reduce: class sums+counts, atomic-free
// ---------------------------------------------------------------------------
__global__ __launch_bounds__(256) void seg_part(
    const float* __restrict__ emb, const int* __restrict__ labels,
    float* __restrict__ psum, float* __restrict__ pcnt) {
  int b = blockIdx.x;                      // 128c * 2half * 8slice
  int c = b >> 4, half = (b >> 3) & 1, slice = b & 7;
  int t = threadIdx.x, w = t >> 6, lane = t & 63;
  int col = half * 256 + w * 64 + lane;
  int r0 = slice * 4096;
  float acc = 0.f; int cnt = 0;
  int lab = labels[r0 + lane];
  for (int ch = 0; ch < 64; ++ch) {
    int nxt = (ch < 63) ? labels[r0 + (ch + 1) * 64 + lane] : 0;
    unsigned long long m = __ballot(lab == c);
    cnt += __popcll(m);
    int rb = r0 + ch * 64;
    while (m) {
      int j = __builtin_ctzll(m); m &= m - 1;
      acc += emb[(size_t)(rb + j) * D + col];
    }
    lab = nxt;
  }
  psum[(size_t)(c * 8 + slice) * D + col] = acc;
  if (half == 0 && t == 0) pcnt[c * 8 + slice] = (float)cnt;
}

__global__ __launch_bounds__(256) void seg_reduce(
    const float* __restrict__ psum, const float* __restrict__ pcnt,
    float* __restrict__ sums, float* __restrict__ cnts) {
  int c = blockIdx.x, t = threadIdx.x;
  for (int h = 0; h < 2; ++h) {
    int col = h * 256 + t;
    float s = 0.f;
#pragma unroll
    for (int sl = 0; sl < 8; ++sl) s += psum[(size_t)(c * 8 + sl) * D + col];
    sums[(size_t)c * D + col] = s;
  }
  if (t == 0) {
    float s = 0.f;
    for (int sl = 0; sl < 8; ++sl) s += pcnt[c * 8 + sl];
    cnts[c] = s;
  }
}

// ---------------------------------------------------------------------------
// build_x2: per block 32 rows, both passes fused; writes bf16 B-fragment
// arrays Xfp/Xfn: element = x[g*32+(lane&31)][s*16+(lane>>5)*8+j]
// at byte ((s*1024+g)*64+lane)*16.
// ---------------------------------------------------------------------------
__global__ __launch_bounds__(256) void build_x2(
    const float* __restrict__ anchor, const float* __restrict__ emb,
    const int* __restrict__ labels, const int* __restrict__ negl,
    const float* __restrict__ sums, const float* __restrict__ cnts,
    unsigned short* __restrict__ Xfp, unsigned short* __restrict__ Xfn) {
  __shared__ float xsp[32 * 257], xsn[32 * 257];
  const int t = threadIdx.x, w = t >> 6, lane = t & 63;
  const int g = blockIdx.x;
  const int r = lane & 31, koff = (lane >> 5) * 8;

  for (int kh = 0; kh < 2; ++kh) {
    if (kh) __syncthreads();
#pragma unroll 2
    for (int it = 0; it < 8; ++it) {
      int row = it * 4 + w;
      int R = g * 32 + row;
      int lp = labels[R], ln = negl[R];
      float sp = 1.f / fmaxf(cnts[lp] - 1.f, 1.f);
      float sn = 1.f / fmaxf(cnts[ln], 1.f);
      int c0 = kh * 256 + lane * 4;
      float4 a = *(const float4*)(anchor + (size_t)R * D + c0);
      float4 e = *(const float4*)(emb + (size_t)R * D + c0);
      float4 Sp = *(const float4*)(sums + (size_t)lp * D + c0);
      float4 Sn = *(const float4*)(sums + (size_t)ln * D + c0);
      float4 xp, xn;
      xp.x = a.x - sp * (Sp.x - e.x);  xn.x = a.x - sn * Sn.x;
      xp.y = a.y - sp * (Sp.y - e.y);  xn.y = a.y - sn * Sn.y;
      xp.z = a.z - sp * (Sp.z - e.z);  xn.z = a.z - sn * Sn.z;
      xp.w = a.w - sp * (Sp.w - e.w);  xn.w = a.w - sn * Sn.w;
      *(float4*)(xsp + row * 257 + lane * 4) = xp;
      *(float4*)(xsn + row * 257 + lane * 4) = xn;
    }
    __syncthreads();
#pragma unroll
    for (int c = 0; c < 8; ++c) {
      const float* xs = (c < 4) ? xsp : xsn;
      unsigned short* Xf = (c < 4) ? Xfp : Xfn;
      int sl = w * 4 + (c & 3);
      short8 pk;
#pragma unroll
      for (int j = 0; j < 8; ++j)
        pk[j] = (short)f2bf(xs[r * 257 + sl * 16 + koff + j]);
      int s = kh * 16 + sl;
      *(short8*)((char*)Xf + ((((size_t)s * 1024 + g) * 64 + lane) << 4)) = pk;
    }
  }
}

// ---------------------------------------------------------------------------
// gemm_d2c: barrier-free K-loop. Block = (n-chunk of 128 M rows, resident in
// LDS 128KB) x (512 X rows). 8 waves; wave = 4nt x 2rt 32x32 tiles, K=512
// fully unrolled; B-fragments read straight from global (1KB coalesced wave
// loads, L2/L3 served). Epilogue: d2 partial = sum_n h*(Z + Mld_diag*h),
// written to d2p[chunk][r] (exactly-once, no atomics).
// grid: blockIdx.x = rgroup*4 + chunk ; rgroup 0..63 pos, 64..127 neg.
// ---------------------------------------------------------------------------
__global__ __launch_bounds__(512, 2) void gemm_d2c(
    const unsigned short* __restrict__ Mh, const float* __restrict__ Mld,
    const unsigned short* __restrict__ Xfp, const unsigned short* __restrict__ Xfn,
    float* __restrict__ d2p) {
  __shared__ char smem[128 * 1024 + 512];
  float* MldL = (float*)(smem + 131072);
  const int t = threadIdx.x, w = t >> 6, lane = t & 63;
  const int chunk = blockIdx.x & 3, rgroup = blockIdx.x >> 2;
  const int isNeg = rgroup >> 6, rg = rgroup & 63;
  const unsigned short* Xsrc = isNeg ? Xfn : Xfp;

  // stage M n-chunk once: 128 pieces (s 0..31, ntl 0..3), 16 per wave
#pragma unroll
  for (int c = 0; c < 16; ++c) {
    int idx = w * 16 + c;            // = s*4 + ntl
    int s = idx >> 2, ntl = idx & 3;
    llds16(smem + idx * 1024,
           (const char*)Mh + ((((size_t)(s * 16 + chunk * 4 + ntl)) * 64 + lane) << 4));
  }
  if (t < 128) MldL[t] = Mld[chunk * 128 + t];
  __syncthreads();   // the ONLY barrier

  const int rt0 = rg * 16 + w * 2;   // wave's two r-tiles (of 32 rows)
  f32x16 acc[4][2];
#pragma unroll
  for (int nt = 0; nt < 4; ++nt)
#pragma unroll
    for (int rt = 0; rt < 2; ++rt)
#pragma unroll
      for (int i = 0; i < 16; ++i) acc[nt][rt][i] = 0.f;

#pragma unroll
  for (int s = 0; s < 32; ++s) {
    short8 b0 = *(const short8*)((const char*)Xsrc +
        ((((size_t)s * 1024 + rt0) * 64 + lane) << 4));
    short8 b1 = *(const short8*)((const char*)Xsrc +
        ((((size_t)s * 1024 + rt0 + 1) * 64 + lane) << 4));
    short8 a0 = *(const short8*)(smem + ((s * 4 + 0) << 10) + (lane << 4));
    short8 a1 = *(const short8*)(smem + ((s * 4 + 1) << 10) + (lane << 4));
    short8 a2 = *(const short8*)(smem + ((s * 4 + 2) << 10) + (lane << 4));
    short8 a3 = *(const short8*)(smem + ((s * 4 + 3) << 10) + (lane << 4));
    acc[0][0] = __builtin_amdgcn_mfma_f32_32x32x16_bf16(a0, b0, acc[0][0], 0, 0, 0);
    acc[0][1] = __builtin_amdgcn_mfma_f32_32x32x16_bf16(a0, b1, acc[0][1], 0, 0, 0);
    acc[1][0] = __builtin_amdgcn_mfma_f32_32x32x16_bf16(a1, b0, acc[1][0], 0, 0, 0);
    acc[1][1] = __builtin_amdgcn_mfma_f32_32x32x16_bf16(a1, b1, acc[1][1], 0, 0, 0);
    acc[2][0] = __builtin_amdgcn_mfma_f32_32x32x16_bf16(a2, b0, acc[2][0], 0, 0, 0);
    acc[2][1] = __builtin_amdgcn_mfma_f32_32x32x16_bf16(a2, b1, acc[2][1], 0, 0, 0);
    acc[3][0] = __builtin_amdgcn_mfma_f32_32x32x16_bf16(a3, b0, acc[3][0], 0, 0, 0);
    acc[3][1] = __builtin_amdgcn_mfma_f32_32x32x16_bf16(a3, b1, acc[3][1], 0, 0, 0);
  }

  // epilogue: d2 partial = sum over this chunk's 128 n of h*(Z + Mld*h)
  const int rr = lane & 31, lh = lane >> 5;
  float d2l[2];
#pragma unroll
  for (int rt = 0; rt < 2; ++rt) {
    int rtg = rt0 + rt;
    short4v hb[4][2][2];   // [nt][i>>3][hi] — all indices compile-time
#pragma unroll
    for (int nt = 0; nt < 4; ++nt)
#pragma unroll
      for (int s2 = 0; s2 < 2; ++s2)
#pragma unroll
        for (int hi = 0; hi < 2; ++hi) {
          int s_h = chunk * 8 + nt * 2 + s2;
          hb[nt][s2][hi] = *(const short4v*)((const char*)Xsrc +
              ((((size_t)s_h * 1024 + rtg) * 64 + hi * 32 + rr) << 4) + lh * 8);
        }
    float d2 = 0.f;
#pragma unroll
    for (int nt = 0; nt < 4; ++nt)
#pragma unroll
      for (int i = 0; i < 16; ++i) {
        float hf = bf2f((unsigned short)hb[nt][i >> 3][(i >> 2) & 1][i & 3]);
        float mld = MldL[nt * 32 + 8 * (i >> 2) + (i & 3) + 4 * lh];
        d2 = fmaf(hf, acc[nt][rt][i] + mld * hf, d2);
      }
    d2l[rt] = d2 + __shfl_xor(d2, 32);
  }
  if (lane < 32) {
    size_t base = (size_t)chunk * 65536 + (size_t)isNeg * 32768 + rg * 512 + w * 64;
#pragma unroll
    for (int rt = 0; rt < 2; ++rt) d2p[base + rt * 32 + rr] = d2l[rt];
  }
}

// ---------------------------------------------------------------------------
// loss reduction: sums the 4 n-chunk partials per sample
// ---------------------------------------------------------------------------
__global__ __launch_bounds__(256) void loss_partial(
    const float* __restrict__ d2p, int B, float* __restrict__ partial) {
  int i = blockIdx.x * blockDim.x + threadIdx.x;
  float v = 0.f;
  if (i < B) {
    float p2 = 0.f, n2 = 0.f;
#pragma unroll
    for (int c = 0; c < 4; ++c) {
      p2 += d2p[(size_t)c * 65536 + i];
      n2 += d2p[(size_t)c * 65536 + 32768 + i];
    }
    float dp = sqrtf(fmaxf(p2, 0.f) + EPS);
    float dn = sqrtf(fmaxf(n2, 0.f) + EPS);
    v = fmaxf(dp - dn + MARGIN, 0.f);
  }
  for (int off = 32; off; off >>= 1) v += __shfl_down(v, off);
  __shared__ float ws[4];
  int w = threadIdx.x >> 6, lane = threadIdx.x & 63;
  if (lane == 0) ws[w] = v;
  __syncthreads();
  if (threadIdx.x == 0) partial[blockIdx.x] = ws[0] + ws[1] + ws[2] + ws[3];
}

__global__ __launch_bounds__(256) void loss_final(
    const float* __restrict__ partial, int n, int B, float* __restrict__ out) {
  float v = (threadIdx.x < n) ? partial[threadIdx.x] : 0.f;
  for (int off = 32; off; off >>= 1) v += __shfl_down(v, off);
  __shared__ float ws[4];
  int w = threadIdx.x >> 6, lane = threadIdx.x & 63;
  if (lane == 0) ws[w] = v;
  __syncthreads();
  if (threadIdx.x == 0) out[0] = (ws[0] + ws[1] + ws[2] + ws[3]) / (float)B;
}

extern "C" void kernel_launch(void* const* d_in, const int* in_sizes, int n_in,
                              void* d_out, int out_size, void* d_ws,
                              size_t ws_size, hipStream_t stream) {
  const float* anchor = (const float*)d_in[0];
  const float* emb = (const float*)d_in[1];
  const float* M = (const float*)d_in[2];
  const int* labels = (const int*)d_in[3];
  const int* negl = (const int*)d_in[4];

  char* ws = (char*)d_ws;
  size_t off = 0;
  auto alloc = [&](size_t bytes) {
    char* p = ws + off;
    off += (bytes + 255) & ~(size_t)255;
    return p;
  };
  unsigned short* Mh = (unsigned short*)alloc((size_t)512 * 512 * 2);
  float* Mld = (float*)alloc((size_t)512 * 4);
  float* sums = (float*)alloc((size_t)C * D * 4);
  float* cnts = (float*)alloc((size_t)C * 4);
  float* psum = (float*)alloc((size_t)C * 8 * D * 4);
  float* pcnt = (float*)alloc((size_t)C * 8 * 4);
  unsigned short* Xfp = (unsigned short*)alloc((size_t)32 * 1024 * 64 * 16);  // 32 MB
  unsigned short* Xfn = (unsigned short*)alloc((size_t)32 * 1024 * 64 * 16);  // 32 MB
  float* d2p = (float*)alloc((size_t)4 * 65536 * 4);                          // 1 MB
  float* lpart = (float*)alloc((size_t)(B_TOT / 256) * 4);

  prep_m<<<128, 256, 0, stream>>>(M, Mh, Mld);
  seg_part<<<2048, 256, 0, stream>>>(emb, labels, psum, pcnt);
  seg_reduce<<<128, 256, 0, stream>>>(psum, pcnt, sums, cnts);
  build_x2<<<1024, 256, 0, stream>>>(anchor, emb, labels, negl, sums, cnts, Xfp, Xfn);
  gemm_d2c<<<512, 512, 0, stream>>>(Mh, Mld, Xfp, Xfn, d2p);
  loss_partial<<<B_TOT / 256, 256, 0, stream>>>(d2p, B_TOT, lpart);
  loss_final<<<1, 256, 0, stream>>>(lpart, B_TOT / 256, B_TOT, (float*)d_out);
}

// Round 5
// 254.872 us; speedup vs baseline: 4.2661x; 1.0208x over previous
//
#include <hip/hip_runtime.h>
#include <math.h>

#define D 512
#define C 128
#define B_TOT 32768
#define MARGIN 0.1f
#define EPS 1e-12f
#define PERM(x) ((x) ^ (((x) >> 3) & 7))

typedef __attribute__((ext_vector_type(8))) short short8;
typedef __attribute__((ext_vector_type(16))) float f32x16;

__device__ inline unsigned short f2bf(float f) {
  union { float f; unsigned u; } v; v.f = f;
  unsigned r = v.u + 0x7fff + ((v.u >> 16) & 1);   // RNE
  return (unsigned short)(r >> 16);
}
__device__ inline float bf2f(unsigned short h) {
  union { unsigned u; float f; } v; v.u = ((unsigned)h) << 16; return v.f;
}

__device__ inline void llds16(void* lds, const void* g) {
  __builtin_amdgcn_global_load_lds(
      (const __attribute__((address_space(1))) unsigned int*)g,
      (__attribute__((address_space(3))) unsigned int*)lds, 16, 0, 0);
}

// ---------------------------------------------------------------------------
// prep_m: cov_inv fp32 [n][k] -> Mh bf16 MFMA A-fragment linear layout
// (piece p = s*16 + nt ; element = M[nt*32+(lane&31)][s*16+(lane>>5)*8+j])
// plus Mld[512] = fp32 diagonal residual M[i][i] - bf16(M[i][i]).
// ---------------------------------------------------------------------------
__global__ __launch_bounds__(256) void prep_m(
    const float* __restrict__ M, unsigned short* __restrict__ Mh,
    float* __restrict__ Mld) {
  int p = blockIdx.x * 4 + (threadIdx.x >> 6);  // piece 0..511
  int lane = threadIdx.x & 63;
  int s = p >> 4, nt = p & 15;
  int n = nt * 32 + (lane & 31), k0 = s * 16 + (lane >> 5) * 8;
  const float4* mp4 = (const float4*)(M + (size_t)n * D + k0);
  float4 m0 = mp4[0], m1 = mp4[1];
  float mv[8] = {m0.x, m0.y, m0.z, m0.w, m1.x, m1.y, m1.z, m1.w};
  short8 hi;
#pragma unroll
  for (int j = 0; j < 8; ++j) hi[j] = (short)f2bf(mv[j]);
  *(short8*)((char*)Mh + (((size_t)p * 64 + lane) << 4)) = hi;
  if (blockIdx.x == 0) {
    for (int i = threadIdx.x; i < 512; i += 256) {
      float v = M[(size_t)i * 513];
      Mld[i] = v - bf2f(f2bf(v));
    }
  }
}

// ---------------------------------------------------------------------------
// seg_part / seg_reduce: class sums+counts, atomic-free
// ---------------------------------------------------------------------------
__global__ __launch_bounds__(256) void seg_part(
    const float* __restrict__ emb, const int* __restrict__ labels,
    float* __restrict__ psum, float* __restrict__ pcnt) {
  int b = blockIdx.x;                      // 128c * 2half * 8slice
  int c = b >> 4, half = (b >> 3) & 1, slice = b & 7;
  int t = threadIdx.x, w = t >> 6, lane = t & 63;
  int col = half * 256 + w * 64 + lane;
  int r0 = slice * 4096;
  float acc = 0.f; int cnt = 0;
  int lab = labels[r0 + lane];
  for (int ch = 0; ch < 64; ++ch) {
    int nxt = (ch < 63) ? labels[r0 + (ch + 1) * 64 + lane] : 0;
    unsigned long long m = __ballot(lab == c);
    cnt += __popcll(m);
    int rb = r0 + ch * 64;
    while (m) {
      int j = __builtin_ctzll(m); m &= m - 1;
      acc += emb[(size_t)(rb + j) * D + col];
    }
    lab = nxt;
  }
  psum[(size_t)(c * 8 + slice) * D + col] = acc;
  if (half == 0 && t == 0) pcnt[c * 8 + slice] = (float)cnt;
}

__global__ __launch_bounds__(256) void seg_reduce(
    const float* __restrict__ psum, const float* __restrict__ pcnt,
    float* __restrict__ sums, float* __restrict__ cnts) {
  int c = blockIdx.x, t = threadIdx.x;
  for (int h = 0; h < 2; ++h) {
    int col = h * 256 + t;
    float s = 0.f;
#pragma unroll
    for (int sl = 0; sl < 8; ++sl) s += psum[(size_t)(c * 8 + sl) * D + col];
    sums[(size_t)c * D + col] = s;
  }
  if (t == 0) {
    float s = 0.f;
    for (int sl = 0; sl < 8; ++sl) s += pcnt[c * 8 + sl];
    cnts[c] = s;
  }
}

// ---------------------------------------------------------------------------
// build_x2: per block 32 rows, both passes fused; writes bf16 B-fragment
// arrays Xfp/Xfn: element = x[g*32+(lane&31)][s*16+(lane>>5)*8+j]
// at byte ((s*1024+g)*64+lane)*16.
// ---------------------------------------------------------------------------
__global__ __launch_bounds__(256) void build_x2(
    const float* __restrict__ anchor, const float* __restrict__ emb,
    const int* __restrict__ labels, const int* __restrict__ negl,
    const float* __restrict__ sums, const float* __restrict__ cnts,
    unsigned short* __restrict__ Xfp, unsigned short* __restrict__ Xfn) {
  __shared__ float xsp[32 * 257], xsn[32 * 257];
  const int t = threadIdx.x, w = t >> 6, lane = t & 63;
  const int g = blockIdx.x;
  const int r = lane & 31, koff = (lane >> 5) * 8;

  for (int kh = 0; kh < 2; ++kh) {
    if (kh) __syncthreads();
#pragma unroll 2
    for (int it = 0; it < 8; ++it) {
      int row = it * 4 + w;
      int R = g * 32 + row;
      int lp = labels[R], ln = negl[R];
      float sp = 1.f / fmaxf(cnts[lp] - 1.f, 1.f);
      float sn = 1.f / fmaxf(cnts[ln], 1.f);
      int c0 = kh * 256 + lane * 4;
      float4 a = *(const float4*)(anchor + (size_t)R * D + c0);
      float4 e = *(const float4*)(emb + (size_t)R * D + c0);
      float4 Sp = *(const float4*)(sums + (size_t)lp * D + c0);
      float4 Sn = *(const float4*)(sums + (size_t)ln * D + c0);
      float4 xp, xn;
      xp.x = a.x - sp * (Sp.x - e.x);  xn.x = a.x - sn * Sn.x;
      xp.y = a.y - sp * (Sp.y - e.y);  xn.y = a.y - sn * Sn.y;
      xp.z = a.z - sp * (Sp.z - e.z);  xn.z = a.z - sn * Sn.z;
      xp.w = a.w - sp * (Sp.w - e.w);  xn.w = a.w - sn * Sn.w;
      *(float4*)(xsp + row * 257 + lane * 4) = xp;
      *(float4*)(xsn + row * 257 + lane * 4) = xn;
    }
    __syncthreads();
#pragma unroll
    for (int c = 0; c < 8; ++c) {
      const float* xs = (c < 4) ? xsp : xsn;
      unsigned short* Xf = (c < 4) ? Xfp : Xfn;
      int sl = w * 4 + (c & 3);
      short8 pk;
#pragma unroll
      for (int j = 0; j < 8; ++j)
        pk[j] = (short)f2bf(xs[r * 257 + sl * 16 + koff + j]);
      int s = kh * 16 + sl;
      *(short8*)((char*)Xf + ((((size_t)s * 1024 + g) * 64 + lane) << 4)) = pk;
    }
  }
}

// ---------------------------------------------------------------------------
// gemm_d2x: X-resident / M-streamed. Block = 128 rows of X resident in LDS
// (128KB, lane-permuted at stage time so both MFMA b128 reads and the
// contraction b32 reads are conflict-free). M streamed global->register with
// ring-4 prefetch (M is 512KB -> L2-hot across all blocks). Each wave owns 2
// n-tiles (32 n each): K-loop (32 MFMA x 4 r-tiles) then inline contraction
// d2 += h*(Z + Mld_diag*h), re-using the accumulators for the next n-tile.
// d2 completes per block -> direct store, no partials.
// ---------------------------------------------------------------------------
__global__ __launch_bounds__(512, 2) void gemm_d2x(
    const unsigned short* __restrict__ Mh, const float* __restrict__ Mld,
    const unsigned short* __restrict__ Xfp, const unsigned short* __restrict__ Xfn,
    float* __restrict__ d2out) {
  __shared__ char smem[131072];
  __shared__ float mldl[512];
  __shared__ float red[8][128];
  const int t = threadIdx.x, w = t >> 6, lane = t & 63;
  const int gb = blockIdx.x;               // 0..511 ; >=256 -> neg
  const int isNeg = gb >> 8, g = gb & 255;
  const unsigned short* Xsrc = isNeg ? Xfn : Xfp;
  const int pl = PERM(lane);

  // stage X slice once: 128 pieces (idx = s*4+rt), source lane-permuted
#pragma unroll
  for (int c = 0; c < 16; ++c) {
    int idx = w * 16 + c;
    int s = idx >> 2, rt = idx & 3;
    llds16(smem + idx * 1024,
           (const char*)Xsrc + ((((size_t)s * 1024 + g * 4 + rt) * 64 + pl) << 4));
  }
  mldl[t] = Mld[t];
  __syncthreads();   // the only pre-epilogue barrier

  const int lh = lane >> 5, l31 = lane & 31;
  float d2p[4] = {0.f, 0.f, 0.f, 0.f};

#pragma unroll
  for (int ni = 0; ni < 2; ++ni) {
    const int ntg = w * 2 + ni;
    float mldv[16];
#pragma unroll
    for (int i = 0; i < 16; ++i)
      mldv[i] = mldl[ntg * 32 + (i & 3) + 8 * (i >> 2) + 4 * lh];

    f32x16 acc[4];
#pragma unroll
    for (int rt = 0; rt < 4; ++rt)
#pragma unroll
      for (int i = 0; i < 16; ++i) acc[rt][i] = 0.f;

    // K loop: A ring-4 global prefetch, B LDS double-buffer
    short8 areg[4];
#pragma unroll
    for (int q = 0; q < 4; ++q)
      areg[q] = *(const short8*)((const char*)Mh +
          ((((size_t)q * 16 + ntg) * 64 + lane) << 4));
    short8 breg[2][4];
#pragma unroll
    for (int rt = 0; rt < 4; ++rt)
      breg[0][rt] = *(const short8*)(smem + (rt << 10) + (pl << 4));

#pragma unroll
    for (int s = 0; s < 32; ++s) {
      if (s < 31) {
#pragma unroll
        for (int rt = 0; rt < 4; ++rt)
          breg[(s + 1) & 1][rt] =
              *(const short8*)(smem + (((s + 1) * 4 + rt) << 10) + (pl << 4));
      }
      short8 av = areg[s & 3];
      if (s < 28)
        areg[s & 3] = *(const short8*)((const char*)Mh +
            ((((size_t)(s + 4) * 16 + ntg) * 64 + lane) << 4));
#pragma unroll
      for (int rt = 0; rt < 4; ++rt)
        acc[rt] = __builtin_amdgcn_mfma_f32_32x32x16_bf16(av, breg[s & 1][rt],
                                                          acc[rt], 0, 0, 0);
    }

    // contraction: d2 += h*(Z + mld*h); h read b32-paired from resident X
#pragma unroll
    for (int rt = 0; rt < 4; ++rt) {
      float dd = 0.f;
#pragma unroll
      for (int i2 = 0; i2 < 8; ++i2) {
        const int i = i2 * 2;
        const int sh = 2 * ntg + (i >> 3);
        const int lp = l31 + 32 * ((i >> 2) & 1);
        const int dw = ((i & 3) >> 1) + 2 * lh;
        unsigned u = *(const unsigned*)(smem + ((sh * 4 + rt) << 10) +
                                        (PERM(lp) << 4) + dw * 4);
        float hlo = bf2f((unsigned short)(u & 0xffffu));
        float hhi = bf2f((unsigned short)(u >> 16));
        dd = fmaf(hlo, acc[rt][i] + mldv[i] * hlo, dd);
        dd = fmaf(hhi, acc[rt][i + 1] + mldv[i + 1] * hhi, dd);
      }
      d2p[rt] += dd;
    }
  }

#pragma unroll
  for (int rt = 0; rt < 4; ++rt) d2p[rt] += __shfl_xor(d2p[rt], 32);
  if (lane < 32) {
#pragma unroll
    for (int rt = 0; rt < 4; ++rt) red[w][rt * 32 + l31] = d2p[rt];
  }
  __syncthreads();
  if (t < 128) {
    float sv = 0.f;
#pragma unroll
    for (int k = 0; k < 8; ++k) sv += red[k][t];
    d2out[(size_t)isNeg * B_TOT + g * 128 + t] = sv;
  }
}

// ---------------------------------------------------------------------------
// loss reduction
// ---------------------------------------------------------------------------
__global__ __launch_bounds__(256) void loss_partial(
    const float* __restrict__ d2, int B, float* __restrict__ partial) {
  int i = blockIdx.x * blockDim.x + threadIdx.x;
  float v = 0.f;
  if (i < B) {
    float dp = sqrtf(fmaxf(d2[i], 0.f) + EPS);
    float dn = sqrtf(fmaxf(d2[B + i], 0.f) + EPS);
    v = fmaxf(dp - dn + MARGIN, 0.f);
  }
  for (int off = 32; off; off >>= 1) v += __shfl_down(v, off);
  __shared__ float ws[4];
  int w = threadIdx.x >> 6, lane = threadIdx.x & 63;
  if (lane == 0) ws[w] = v;
  __syncthreads();
  if (threadIdx.x == 0) partial[blockIdx.x] = ws[0] + ws[1] + ws[2] + ws[3];
}

__global__ __launch_bounds__(256) void loss_final(
    const float* __restrict__ partial, int n, int B, float* __restrict__ out) {
  float v = (threadIdx.x < n) ? partial[threadIdx.x] : 0.f;
  for (int off = 32; off; off >>= 1) v += __shfl_down(v, off);
  __shared__ float ws[4];
  int w = threadIdx.x >> 6, lane = threadIdx.x & 63;
  if (lane == 0) ws[w] = v;
  __syncthreads();
  if (threadIdx.x == 0) out[0] = (ws[0] + ws[1] + ws[2] + ws[3]) / (float)B;
}

extern "C" void kernel_launch(void* const* d_in, const int* in_sizes, int n_in,
                              void* d_out, int out_size, void* d_ws,
                              size_t ws_size, hipStream_t stream) {
  const float* anchor = (const float*)d_in[0];
  const float* emb = (const float*)d_in[1];
  const float* M = (const float*)d_in[2];
  const int* labels = (const int*)d_in[3];
  const int* negl = (const int*)d_in[4];

  char* ws = (char*)d_ws;
  size_t off = 0;
  auto alloc = [&](size_t bytes) {
    char* p = ws + off;
    off += (bytes + 255) & ~(size_t)255;
    return p;
  };
  unsigned short* Mh = (unsigned short*)alloc((size_t)512 * 512 * 2);
  float* Mld = (float*)alloc((size_t)512 * 4);
  float* sums = (float*)alloc((size_t)C * D * 4);
  float* cnts = (float*)alloc((size_t)C * 4);
  float* psum = (float*)alloc((size_t)C * 8 * D * 4);
  float* pcnt = (float*)alloc((size_t)C * 8 * 4);
  unsigned short* Xfp = (unsigned short*)alloc((size_t)32 * 1024 * 64 * 16);  // 32 MB
  unsigned short* Xfn = (unsigned short*)alloc((size_t)32 * 1024 * 64 * 16);  // 32 MB
  float* d2 = (float*)alloc((size_t)2 * B_TOT * 4);
  float* lpart = (float*)alloc((size_t)(B_TOT / 256) * 4);

  prep_m<<<128, 256, 0, stream>>>(M, Mh, Mld);
  seg_part<<<2048, 256, 0, stream>>>(emb, labels, psum, pcnt);
  seg_reduce<<<128, 256, 0, stream>>>(psum, pcnt, sums, cnts);
  build_x2<<<1024, 256, 0, stream>>>(anchor, emb, labels, negl, sums, cnts, Xfp, Xfn);
  gemm_d2x<<<512, 512, 0, stream>>>(Mh, Mld, Xfp, Xfn, d2);
  loss_partial<<<B_TOT / 256, 256, 0, stream>>>(d2, B_TOT, lpart);
  loss_final<<<1, 256, 0, stream>>>(lpart, B_TOT / 256, B_TOT, (float*)d_out);
}